// Round 16
// baseline (131.099 us; speedup 1.0000x reference)
//
#include <hip/hip_runtime.h>

typedef unsigned short u16;
typedef __bf16 bf16x8 __attribute__((ext_vector_type(8)));
typedef float f32x4 __attribute__((ext_vector_type(4)));
typedef unsigned short u16x8 __attribute__((ext_vector_type(8)));
typedef unsigned short u16x4 __attribute__((ext_vector_type(4)));

__device__ __forceinline__ float bf2f(u16 u){
  union { unsigned i; float f; } v; v.i = ((unsigned)u) << 16; return v.f;
}
__device__ __forceinline__ u16 f2bf(float f){
  union { float f; unsigned i; } v; v.f = f;
  unsigned r = v.i + 0x7FFFu + ((v.i >> 16) & 1u);
  return (u16)(r >> 16);
}
// elu(x)+1:  x>0 -> x+1 ; x<=0 -> exp(x)
__device__ __forceinline__ float elup(float x){ return x > 0.f ? x + 1.f : expf(x); }

__device__ __forceinline__ void gload_lds16(const void* gsrc, void* ldst){
  __builtin_amdgcn_global_load_lds(
      (__attribute__((address_space(1))) void*)(unsigned long long)gsrc,
      (__attribute__((address_space(3))) void*)(unsigned)(unsigned long long)ldst,
      16, 0, 0);
}

struct TD { const float* in; u16* out; int R, Cc, cx, ntiles; };

// 64x64 transpose+cast tile body (256 threads): reads 256B segs, writes 128B segs
__device__ __forceinline__ void transpose_tile(const TD& d, int bb, int tid, u16 (*tile)[65]){
  int c0 = (bb % d.cx) * 64, r0 = (bb / d.cx) * 64;
  int tx = tid & 63, ty = tid >> 6; // 64 x 4
  #pragma unroll
  for (int i=0;i<16;i++)
    tile[tx][ty + i*4] = f2bf(d.in[(size_t)(r0 + ty + i*4)*d.Cc + c0 + tx]);
  __syncthreads();
  #pragma unroll
  for (int i=0;i<16;i++)
    d.out[(size_t)(c0 + ty + i*4)*d.R + r0 + tx] = tile[ty + i*4][tx];
}

// ---------------- prep1: qkv_w transpose (768 tiles) + LN1 (2048 rows) ----------------
__global__ __launch_bounds__(256) void prep1(TD t0,
                                             const float* __restrict__ x, const float* __restrict__ g,
                                             const float* __restrict__ b, u16* __restrict__ y){
  __shared__ u16 tile[64][65];
  __shared__ float ls[4], ls2[4];
  int bidx = blockIdx.x, tid = threadIdx.x;
  if (bidx >= 768){
    int row = bidx - 768;
    size_t base = (size_t)row*1024 + tid*4;
    f32x4 xv = *(const f32x4*)(x + base);
    float v0=xv[0], v1=xv[1], v2=xv[2], v3=xv[3];
    float s  = v0+v1+v2+v3;
    float s2 = v0*v0+v1*v1+v2*v2+v3*v3;
    #pragma unroll
    for (int off=32; off>0; off>>=1){ s += __shfl_xor(s, off); s2 += __shfl_xor(s2, off); }
    if ((tid & 63) == 0){ ls[tid>>6] = s; ls2[tid>>6] = s2; }
    __syncthreads();
    float ts = ls[0]+ls[1]+ls[2]+ls[3];
    float ts2 = ls2[0]+ls2[1]+ls2[2]+ls2[3];
    float mean = ts*(1.f/1024.f);
    float var  = ts2*(1.f/1024.f) - mean*mean;
    float rstd = rsqrtf(var + 1e-5f);
    f32x4 gv = *(const f32x4*)(g + tid*4);
    f32x4 bv = *(const f32x4*)(b + tid*4);
    u16x4 ov;
    ov[0]=f2bf((v0-mean)*rstd*gv[0]+bv[0]);
    ov[1]=f2bf((v1-mean)*rstd*gv[1]+bv[1]);
    ov[2]=f2bf((v2-mean)*rstd*gv[2]+bv[2]);
    ov[3]=f2bf((v3-mean)*rstd*gv[3]+bv[3]);
    *(u16x4*)(y + base) = ov;
    return;
  }
  transpose_tile(t0, bidx, tid, tile);
}

// ---------------- fused split-K reduce(+bias+residual) -> x2 (f32) AND LayerNorm -> h2 (bf16) ----------------
__global__ __launch_bounds__(256) void ln2_fused(const u16* __restrict__ P0, const u16* __restrict__ P1,
                                                 const u16* __restrict__ P2, const u16* __restrict__ P3,
                                                 const float* __restrict__ bias, const float* __restrict__ xres,
                                                 const float* __restrict__ g, const float* __restrict__ b,
                                                 float* __restrict__ x2, u16* __restrict__ h2){
  int row = blockIdx.x, tid = threadIdx.x;
  size_t base = (size_t)row*1024 + tid*4;
  u16x4 a0 = *(const u16x4*)(P0 + base);
  u16x4 a1 = *(const u16x4*)(P1 + base);
  u16x4 a2 = *(const u16x4*)(P2 + base);
  u16x4 a3 = *(const u16x4*)(P3 + base);
  f32x4 rv = *(const f32x4*)(xres + base);
  f32x4 bv = *(const f32x4*)(bias + tid*4);
  f32x4 v;
  #pragma unroll
  for (int j=0;j<4;j++) v[j] = (bf2f(a0[j])+bf2f(a1[j])) + (bf2f(a2[j])+bf2f(a3[j])) + bv[j] + rv[j];
  *(f32x4*)(x2 + base) = v;
  float s  = v[0]+v[1]+v[2]+v[3];
  float s2 = v[0]*v[0]+v[1]*v[1]+v[2]*v[2]+v[3]*v[3];
  #pragma unroll
  for (int off=32; off>0; off>>=1){ s += __shfl_xor(s, off); s2 += __shfl_xor(s2, off); }
  __shared__ float ls[4], ls2[4];
  if ((tid & 63) == 0){ ls[tid>>6] = s; ls2[tid>>6] = s2; }
  __syncthreads();
  float ts = ls[0]+ls[1]+ls[2]+ls[3];
  float ts2 = ls2[0]+ls2[1]+ls2[2]+ls2[3];
  float mean = ts*(1.f/1024.f);
  float var  = ts2*(1.f/1024.f) - mean*mean;
  float rstd = rsqrtf(var + 1e-5f);
  f32x4 gv = *(const f32x4*)(g + tid*4);
  f32x4 bb = *(const f32x4*)(b + tid*4);
  u16x4 ov;
  #pragma unroll
  for (int j=0;j<4;j++) ov[j] = f2bf((v[j]-mean)*rstd*gv[j]+bb[j]);
  *(u16x4*)(h2 + base) = ov;
}

// ---------------- GEMM: C[M][N] = A[M][K] * BT[N][K]^T (+ bias) ----------------
// 128x128 tile, BK=64, double-buffered LDS, T2 both-sides XOR swizzle, T1 XCD block swizzle.
// NW=8: 8 waves (512 thr), 32x64 per wave (proven r10 config, 16 waves/CU).
// NW=4: 4 waves (256 thr), 64x64 per wave — 2x MFMA per ds_read/barrier, 8 waves/CU.
// EPI 0: +bias -> bf16.  1: gelu(+bias) -> bf16.  3: split-K bf16 PARTIAL (no bias), z at out+z*pstride.
template<int EPI, int NW>
__global__ __launch_bounds__(NW*64, (NW==8) ? 4 : 2) void gemm_bt(
    const u16* __restrict__ A, const u16* __restrict__ BT,
    const float* __restrict__ bias, const float* __restrict__ res,
    void* __restrict__ out, int N, int K, size_t pstride){
  __shared__ u16 As[2][128*64];
  __shared__ u16 Bs[2][128*64];
  constexpr int MI = (NW==8) ? 2 : 4;
  int tid = threadIdx.x;
  int w = tid >> 6, lane = tid & 63;

  unsigned flat = blockIdx.x + gridDim.x*(blockIdx.y + gridDim.y*blockIdx.z);
  unsigned nwg  = gridDim.x*gridDim.y*gridDim.z;
  unsigned logical = (flat & 7)*(nwg >> 3) + (flat >> 3);
  unsigned bx = logical % gridDim.x;
  unsigned rem = logical / gridDim.x;
  unsigned by = rem % gridDim.y;
  unsigned bz = rem / gridDim.y;

  int m0 = bx * 128, n0 = by * 128;
  int Kc = K / gridDim.z;
  int kbase = bz * Kc;
  int nt = Kc / 64;

  f32x4 acc[MI][4] = {};

  int l3 = lane >> 3, l7 = lane & 7;
  const u16* aSrc; const u16* bSrc;
  int r0, c0;
  if constexpr (NW==8){
    aSrc = A  + (size_t)(m0 + w*16 + l3)*K + kbase + (l7 ^ l3)*8;
    bSrc = BT + (size_t)(n0 + w*16 + l3)*K + kbase + (l7 ^ l3)*8;
    r0 = (w>>1)*32; c0 = (w&1)*64;
  } else {
    aSrc = A  + (size_t)(m0 + w*8 + l3)*K + kbase + (l7 ^ l3)*8;
    bSrc = BT + (size_t)(n0 + w*8 + l3)*K + kbase + (l7 ^ l3)*8;
    r0 = (w>>1)*64; c0 = (w&1)*64;
  }
  int lrow = lane & 15, g4 = lane >> 4;
  int swz = (lrow & 7) << 4;

  auto STAGE = [&](int kt, int buf){
    int k0 = kt*64;
    if constexpr (NW==8){
      u16* aD = As[buf] + w*16*64;
      u16* bD = Bs[buf] + w*16*64;
      gload_lds16(aSrc + k0,               aD);
      gload_lds16(aSrc + (size_t)8*K + k0, aD + 8*64);
      gload_lds16(bSrc + k0,               bD);
      gload_lds16(bSrc + (size_t)8*K + k0, bD + 8*64);
    } else {
      u16* aD = As[buf] + w*8*64;
      u16* bD = Bs[buf] + w*8*64;
      #pragma unroll
      for (int i=0;i<4;i++){
        gload_lds16(aSrc + (size_t)(32*i)*K + k0, aD + i*32*64);
        gload_lds16(bSrc + (size_t)(32*i)*K + k0, bD + i*32*64);
      }
    }
  };
  auto COMPUTE = [&](int buf){
    const char* Ab = (const char*)As[buf];
    const char* Bb = (const char*)Bs[buf];
    #pragma unroll
    for (int kk=0; kk<2; kk++){
      int ko = (kk*64 + g4*16) ^ swz;
      bf16x8 af[MI], bfv[4];
      #pragma unroll
      for (int mi=0;mi<MI;mi++) af[mi]  = *(const bf16x8*)(Ab + (r0 + mi*16 + lrow)*128 + ko);
      #pragma unroll
      for (int ni=0;ni<4;ni++)  bfv[ni] = *(const bf16x8*)(Bb + (c0 + ni*16 + lrow)*128 + ko);
      #pragma unroll
      for (int mi=0;mi<MI;mi++)
        #pragma unroll
        for (int ni=0;ni<4;ni++)
          acc[mi][ni] = __builtin_amdgcn_mfma_f32_16x16x32_bf16(af[mi], bfv[ni], acc[mi][ni], 0, 0, 0);
    }
  };

  STAGE(0, 0);
  __syncthreads();
  int cur = 0;
  for (int t = 0; t < nt; ++t){
    if (t + 1 < nt) STAGE(t+1, cur^1);
    COMPUTE(cur);
    __syncthreads();
    cur ^= 1;
  }

  int lgr = lane >> 4;
  u16* pout = (EPI == 3) ? ((u16*)out + (size_t)bz * pstride) : (u16*)out;
  #pragma unroll
  for (int mi=0;mi<MI;mi++){
    #pragma unroll
    for (int j=0;j<4;j++){
      int row = m0 + r0 + mi*16 + lgr*4 + j;
      #pragma unroll
      for (int ni=0;ni<4;ni++){
        int col = n0 + c0 + ni*16 + lrow;
        size_t idx = (size_t)row*N + col;
        if constexpr (EPI == 3){
          pout[idx] = f2bf(acc[mi][ni][j]);
        } else {
          float v = acc[mi][ni][j] + bias[col];
          if constexpr (EPI == 0){
            ((u16*)out)[idx] = f2bf(v);
          } else {
            v = 0.5f * v * (1.f + erff(v * 0.70710678118654752f));
            ((u16*)out)[idx] = f2bf(v);
          }
        }
      }
    }
  }
}

// ---------------- split-K reduction: out = sum(4 partials) + bias + res (f32 out) ----------------
__global__ __launch_bounds__(256) void reduce4(const u16* __restrict__ P0, const u16* __restrict__ P1,
                                               const u16* __restrict__ P2, const u16* __restrict__ P3,
                                               const float* __restrict__ bias, const float* __restrict__ res,
                                               float* __restrict__ out){
  size_t i = ((size_t)blockIdx.x*256 + threadIdx.x)*4;
  u16x4 a = *(const u16x4*)(P0 + i);
  u16x4 b = *(const u16x4*)(P1 + i);
  u16x4 c = *(const u16x4*)(P2 + i);
  u16x4 d = *(const u16x4*)(P3 + i);
  f32x4 rv = *(const f32x4*)(res + i);
  f32x4 bv = *(const f32x4*)(bias + (i & 1023));
  f32x4 o;
  #pragma unroll
  for (int j=0;j<4;j++) o[j] = (bf2f(a[j]) + bf2f(b[j])) + (bf2f(c[j]) + bf2f(d[j])) + bv[j] + rv[j];
  *(f32x4*)(out + i) = o;
}

// ---------------- attention: S^T chunk sums + Ks sums, WITH 3 weight transposes riding the grid ----------------
__global__ __launch_bounds__(256) void attn_chunksum(TD d1, TD d2, TD d3,
                                                     const u16* __restrict__ qkv,
                                                     float* __restrict__ S, float* __restrict__ Ks){
  __shared__ u16 KT[64*72];  // [d][t] bf16, elup'd  (transpose path reuses as 64x65 tile)
  __shared__ u16 VT[64*72];  // [e][t] bf16 (raw)
  int bidx = blockIdx.x, tid = threadIdx.x;
  if (bidx >= 512){
    int bb = bidx - 512;
    TD d;
    if (bb < d1.ntiles) d = d1;
    else { bb -= d1.ntiles;
      if (bb < d2.ntiles) d = d2;
      else { bb -= d2.ntiles; d = d3; } }
    transpose_tile(d, bb, tid, (u16(*)[65])KT);
    return;
  }
  int c = bidx & 31, h = bidx >> 5;
  int t = tid >> 2, seg = tid & 3, e0 = seg*16;
  size_t rowb = (size_t)(c*64 + t)*3072 + h*64 + e0;
  u16x8 k0 = *(const u16x8*)(qkv + rowb + 1024);
  u16x8 k1 = *(const u16x8*)(qkv + rowb + 1032);
  u16x8 v0 = *(const u16x8*)(qkv + rowb + 2048);
  u16x8 v1 = *(const u16x8*)(qkv + rowb + 2056);
  #pragma unroll
  for (int i=0;i<8;i++){
    KT[(e0 + i)*72 + t]     = f2bf(elup(bf2f(k0[i])));
    KT[(e0 + 8 + i)*72 + t] = f2bf(elup(bf2f(k1[i])));
    VT[(e0 + i)*72 + t]     = v0[i];
    VT[(e0 + 8 + i)*72 + t] = v1[i];
  }
  __syncthreads();

  int w = tid >> 6, lane = tid & 63;
  int lr = lane & 15, lk = (lane>>4)*8, g = lane >> 4, cl = lane & 15;
  bf16x8 av_[2];
  #pragma unroll
  for (int kk=0;kk<2;kk++) av_[kk] = *(const bf16x8*)(VT + (w*16 + lr)*72 + kk*32 + lk);
  f32x4 acc[4] = {};
  #pragma unroll
  for (int di=0;di<4;di++){
    #pragma unroll
    for (int kk=0;kk<2;kk++){
      bf16x8 bk = *(const bf16x8*)(KT + (di*16 + lr)*72 + kk*32 + lk);
      acc[di] = __builtin_amdgcn_mfma_f32_16x16x32_bf16(av_[kk], bk, acc[di], 0, 0, 0);
    }
  }
  size_t base = (size_t)(h*32 + c)*4096;
  #pragma unroll
  for (int di=0;di<4;di++)
    #pragma unroll
    for (int j=0;j<4;j++)
      S[base + (size_t)(w*16 + g*4 + j)*64 + di*16 + cl] = acc[di][j];

  float s = 0.f;
  #pragma unroll
  for (int i=0;i<16;i++) s += bf2f(KT[t*72 + e0 + i]);
  s += __shfl_xor(s, 1); s += __shfl_xor(s, 2);
  if (seg == 0) Ks[(size_t)(h*32 + c)*64 + t] = s;
}

// ---------------- attention: exclusive prefix over chunks (per head, element-parallel) ----------------
__global__ __launch_bounds__(256) void attn_prefix(float* __restrict__ S, float* __restrict__ Ks){
  int g = blockIdx.x, h = blockIdx.y, tid = threadIdx.x;
  size_t hb = (size_t)h * 32 * 4096;
  int idx = g*256 + tid;
  float run = 0.f;
  for (int c=0; c<32; c++){
    size_t p = hb + (size_t)c*4096 + idx;
    float v = S[p]; S[p] = run; run += v;
  }
  if (g == 0 && tid < 64){
    float r2 = 0.f;
    for (int c=0; c<32; c++){
      size_t p = (size_t)(h*32 + c)*64 + tid;
      float v = Ks[p]; Ks[p] = r2; r2 += v;
    }
  }
}

// ---------------- attention: O = Q*S_prev^T + tril(QK^T)V, den = Q*kp + rowsum(A); MFMA ----------------
__global__ __launch_bounds__(256) void attn_out(const u16* __restrict__ qkv, const float* __restrict__ S,
                                                const float* __restrict__ Ks, u16* __restrict__ o){
  __shared__ u16 Qs [64*72];
  __shared__ u16 Ksh[64*72];
  __shared__ u16 VT [64*72];
  __shared__ u16 SpT[64*72];
  __shared__ u16 Am [64*72];
  __shared__ float kp[64], den[64];
  int c = blockIdx.x, h = blockIdx.y, tid = threadIdx.x;
  int t = tid >> 2, seg = tid & 3, e0 = seg*16;

  size_t rowb = (size_t)(c*64 + t)*3072 + h*64 + e0;
  u16x8 q0 = *(const u16x8*)(qkv + rowb);
  u16x8 q1 = *(const u16x8*)(qkv + rowb + 8);
  u16x8 k0 = *(const u16x8*)(qkv + rowb + 1024);
  u16x8 k1 = *(const u16x8*)(qkv + rowb + 1032);
  u16x8 v0 = *(const u16x8*)(qkv + rowb + 2048);
  u16x8 v1 = *(const u16x8*)(qkv + rowb + 2056);
  #pragma unroll
  for (int i=0;i<8;i++){
    Qs [t*72 + e0 + i]     = f2bf(elup(bf2f(q0[i])));
    Qs [t*72 + e0 + 8 + i] = f2bf(elup(bf2f(q1[i])));
    Ksh[t*72 + e0 + i]     = f2bf(elup(bf2f(k0[i])));
    Ksh[t*72 + e0 + 8 + i] = f2bf(elup(bf2f(k1[i])));
    VT [(e0 + i)*72 + t]     = v0[i];
    VT [(e0 + 8 + i)*72 + t] = v1[i];
  }
  size_t sbase = (size_t)(h*32 + c)*4096;
  {
    const f32x4* sp = (const f32x4*)(S + sbase + (size_t)t*64 + e0);
    #pragma unroll
    for (int qd=0;qd<4;qd++){
      f32x4 v = sp[qd];
      #pragma unroll
      for (int j=0;j<4;j++) SpT[t*72 + e0 + qd*4 + j] = f2bf(v[j]);
    }
  }
  if (tid < 64) kp[tid] = Ks[(size_t)(h*32 + c)*64 + tid];
  __syncthreads();

  int w = tid >> 6, lane = tid & 63;
  int lr = lane & 15, lk = (lane>>4)*8, g = lane >> 4, cl = lane & 15;

  bf16x8 aq[2];
  #pragma unroll
  for (int kk=0;kk<2;kk++) aq[kk] = *(const bf16x8*)(Qs + (w*16 + lr)*72 + kk*32 + lk);

  f32x4 acc[4] = {};
  #pragma unroll
  for (int ni=0;ni<4;ni++){
    #pragma unroll
    for (int kk=0;kk<2;kk++){
      bf16x8 bs = *(const bf16x8*)(SpT + (ni*16 + lr)*72 + kk*32 + lk);
      acc[ni] = __builtin_amdgcn_mfma_f32_16x16x32_bf16(aq[kk], bs, acc[ni], 0, 0, 0);
    }
  }
  #pragma unroll
  for (int si=0;si<4;si++){
    f32x4 qk = {};
    #pragma unroll
    for (int kk=0;kk<2;kk++){
      bf16x8 bk = *(const bf16x8*)(Ksh + (si*16 + lr)*72 + kk*32 + lk);
      qk = __builtin_amdgcn_mfma_f32_16x16x32_bf16(aq[kk], bk, qk, 0, 0, 0);
    }
    #pragma unroll
    for (int j=0;j<4;j++){
      int rowt = w*16 + g*4 + j;
      int scol = si*16 + cl;
      Am[rowt*72 + scol] = f2bf((scol <= rowt) ? qk[j] : 0.f);
    }
  }
  __syncthreads();

  {
    float dsum = 0.f;
    #pragma unroll
    for (int i=0;i<16;i++) dsum += bf2f(Am[t*72 + e0 + i]);
    #pragma unroll
    for (int i=0;i<16;i++) dsum += bf2f(Qs[t*72 + e0 + i]) * kp[e0 + i];
    dsum += __shfl_xor(dsum, 1); dsum += __shfl_xor(dsum, 2);
    if (seg == 0) den[t] = dsum;
  }
  {
    bf16x8 aa[2];
    #pragma unroll
    for (int kk=0;kk<2;kk++) aa[kk] = *(const bf16x8*)(Am + (w*16 + lr)*72 + kk*32 + lk);
    #pragma unroll
    for (int ni=0;ni<4;ni++){
      #pragma unroll
      for (int kk=0;kk<2;kk++){
        bf16x8 bv = *(const bf16x8*)(VT + (ni*16 + lr)*72 + kk*32 + lk);
        acc[ni] = __builtin_amdgcn_mfma_f32_16x16x32_bf16(aa[kk], bv, acc[ni], 0, 0, 0);
      }
    }
  }
  __syncthreads();

  #pragma unroll
  for (int j=0;j<4;j++){
    int rowt = w*16 + g*4 + j;
    float inv = 1.f/(den[rowt] + 1e-6f);
    #pragma unroll
    for (int ni=0;ni<4;ni++)
      o[(size_t)(c*64 + rowt)*1024 + h*64 + ni*16 + cl] = f2bf(acc[ni][j]*inv);
  }
}

// ---------------- launch ----------------
extern "C" void kernel_launch(void* const* d_in, const int* in_sizes, int n_in,
                              void* d_out, int out_size, void* d_ws, size_t ws_size,
                              hipStream_t stream) {
  (void)in_sizes; (void)n_in; (void)out_size; (void)ws_size;
  const float* x     = (const float*)d_in[0];
  const float* qkv_w = (const float*)d_in[1];
  const float* qkv_b = (const float*)d_in[2];
  const float* out_w = (const float*)d_in[3];
  const float* out_b = (const float*)d_in[4];
  const float* ln1_g = (const float*)d_in[5];
  const float* ln1_b = (const float*)d_in[6];
  const float* ln2_g = (const float*)d_in[7];
  const float* ln2_b = (const float*)d_in[8];
  const float* w1    = (const float*)d_in[9];
  const float* b1    = (const float*)d_in[10];
  const float* w2    = (const float*)d_in[11];
  const float* b2    = (const float*)d_in[12];

  char* ws = (char*)d_ws;
  u16*   wT_qkv = (u16*)  (ws);              // [0, 6291456)        dead after qkv GEMM
  u16*   wT_out = (u16*)  (ws +  6291456);   // [6291456, 8388608)  dead after out-proj
  u16*   wT_w1  = (u16*)  (ws +  8388608);   // [8388608, 16777216) dead after MLP1
  u16*   wT_w2  = (u16*)  (ws + 16777216);   // [16777216, 25165824)
  u16*   h1     = (u16*)  (ws + 25165824);   // [25165824, 29360128) bf16; reused as o
  u16*   qkv    = (u16*)  (ws + 29360128);   // [29360128, 41943040) bf16; dead after attn_out
  float* Ssum   = (float*)(ws + 41943040);   // [41943040, 50331648) f32 S^T chunks; dead after attn_out
  float* ksum   = (float*)(ws + 50331648);   // [50331648, 50462720)
  float* x2     = (float*)(ws + 50462720);   // [50462720, 58851328) f32
  u16*   h2     = (u16*)  (ws + 58851328);   // [58851328, 63045632) bf16
  u16*   o      = h1;
  u16*   a1     = qkv;                        // 2048x4096 bf16 over dead qkv+Ssum
  u16*   Pa0    = (u16*)(ws + 29360128);      // out-proj split-4 partials (dead qkv+Ssum, pre-a1)
  size_t PaStride = 2097152;                  // elements
  u16*   Pm0    = (u16*)(ws);                 // MLP2 split-4 partials over dead wT regions
  u16*   Pm1    = (u16*)(ws +  4194304);
  u16*   Pm2    = (u16*)(ws +  8388608);
  u16*   Pm3    = (u16*)(ws + 12582912);
  size_t PmStride = 2097152;                  // elements
  float* outp   = (float*)d_out;

  TD t0{qkv_w, wT_qkv, 1024, 3072,  48,  768};
  TD t1{out_w, wT_out, 1024, 1024,  16,  256};
  TD t2{w1,    wT_w1,  1024, 4096,  64, 1024};
  TD t3{w2,    wT_w2,  4096, 1024,  16, 1024};

  // prep1: qkv_w transpose (768) + LN1 (2048)
  prep1<<<2816, 256, 0, stream>>>(t0, x, ln1_g, ln1_b, h1);

  gemm_bt<0,8><<<dim3(16, 24, 1), 512, 0, stream>>>(h1, wT_qkv, qkv_b, nullptr, qkv, 3072, 1024, 0);

  // chunksum (512 attn blocks) + out_w/w1/w2 transposes (2304 tiles) share one dispatch
  attn_chunksum<<<2816, 256, 0, stream>>>(t1, t2, t3, qkv, Ssum, ksum);
  attn_prefix  <<<dim3(16, 16), 256, 0, stream>>>(Ssum, ksum);
  attn_out     <<<dim3(32, 16), 256, 0, stream>>>(qkv, Ssum, ksum, o);

  gemm_bt<3,8><<<dim3(16, 8, 4), 512, 0, stream>>>(o, wT_out, nullptr, nullptr, Pa0, 1024, 1024, PaStride);
  ln2_fused<<<2048, 256, 0, stream>>>(Pa0, Pa0 + PaStride, Pa0 + 2*PaStride, Pa0 + 3*PaStride,
                                      out_b, x, ln2_g, ln2_b, x2, h2);

  // A/B: MLP1 and MLP2 use the 4-wave 64x64-per-wave variant
  gemm_bt<1,4><<<dim3(16, 32, 1), 256, 0, stream>>>(h2, wT_w1, b1, nullptr, a1, 4096, 1024, 0);

  gemm_bt<3,4><<<dim3(16, 8, 4), 256, 0, stream>>>(a1, wT_w2, nullptr, nullptr, Pm0, 1024, 4096, PmStride);
  reduce4<<<2048, 256, 0, stream>>>(Pm0, Pm1, Pm2, Pm3, b2, x2, outp);
}

// Round 17
// 129.548 us; speedup vs baseline: 1.0120x; 1.0120x over previous
//
#include <hip/hip_runtime.h>

typedef unsigned short u16;
typedef __bf16 bf16x8 __attribute__((ext_vector_type(8)));
typedef float f32x4 __attribute__((ext_vector_type(4)));
typedef unsigned short u16x8 __attribute__((ext_vector_type(8)));
typedef unsigned short u16x4 __attribute__((ext_vector_type(4)));

__device__ __forceinline__ float bf2f(u16 u){
  union { unsigned i; float f; } v; v.i = ((unsigned)u) << 16; return v.f;
}
__device__ __forceinline__ u16 f2bf(float f){
  union { float f; unsigned i; } v; v.f = f;
  unsigned r = v.i + 0x7FFFu + ((v.i >> 16) & 1u);
  return (u16)(r >> 16);
}
// elu(x)+1:  x>0 -> x+1 ; x<=0 -> exp(x)
__device__ __forceinline__ float elup(float x){ return x > 0.f ? x + 1.f : expf(x); }

__device__ __forceinline__ void gload_lds16(const void* gsrc, void* ldst){
  __builtin_amdgcn_global_load_lds(
      (__attribute__((address_space(1))) void*)(unsigned long long)gsrc,
      (__attribute__((address_space(3))) void*)(unsigned)(unsigned long long)ldst,
      16, 0, 0);
}

struct TD { const float* in; u16* out; int R, Cc, cx, ntiles; };

// 64x64 transpose+cast tile body (256 threads): reads 256B segs, writes 128B segs
__device__ __forceinline__ void transpose_tile(const TD& d, int bb, int tid, u16 (*tile)[65]){
  int c0 = (bb % d.cx) * 64, r0 = (bb / d.cx) * 64;
  int tx = tid & 63, ty = tid >> 6; // 64 x 4
  #pragma unroll
  for (int i=0;i<16;i++)
    tile[tx][ty + i*4] = f2bf(d.in[(size_t)(r0 + ty + i*4)*d.Cc + c0 + tx]);
  __syncthreads();
  #pragma unroll
  for (int i=0;i<16;i++)
    d.out[(size_t)(c0 + ty + i*4)*d.R + r0 + tx] = tile[ty + i*4][tx];
}

// ---------------- prep1: qkv_w transpose (768 tiles) + LN1 (2048 rows) ----------------
__global__ __launch_bounds__(256) void prep1(TD t0,
                                             const float* __restrict__ x, const float* __restrict__ g,
                                             const float* __restrict__ b, u16* __restrict__ y){
  __shared__ u16 tile[64][65];
  __shared__ float ls[4], ls2[4];
  int bidx = blockIdx.x, tid = threadIdx.x;
  if (bidx >= 768){
    int row = bidx - 768;
    size_t base = (size_t)row*1024 + tid*4;
    f32x4 xv = *(const f32x4*)(x + base);
    float v0=xv[0], v1=xv[1], v2=xv[2], v3=xv[3];
    float s  = v0+v1+v2+v3;
    float s2 = v0*v0+v1*v1+v2*v2+v3*v3;
    #pragma unroll
    for (int off=32; off>0; off>>=1){ s += __shfl_xor(s, off); s2 += __shfl_xor(s2, off); }
    if ((tid & 63) == 0){ ls[tid>>6] = s; ls2[tid>>6] = s2; }
    __syncthreads();
    float ts = ls[0]+ls[1]+ls[2]+ls[3];
    float ts2 = ls2[0]+ls2[1]+ls2[2]+ls2[3];
    float mean = ts*(1.f/1024.f);
    float var  = ts2*(1.f/1024.f) - mean*mean;
    float rstd = rsqrtf(var + 1e-5f);
    f32x4 gv = *(const f32x4*)(g + tid*4);
    f32x4 bv = *(const f32x4*)(b + tid*4);
    u16x4 ov;
    ov[0]=f2bf((v0-mean)*rstd*gv[0]+bv[0]);
    ov[1]=f2bf((v1-mean)*rstd*gv[1]+bv[1]);
    ov[2]=f2bf((v2-mean)*rstd*gv[2]+bv[2]);
    ov[3]=f2bf((v3-mean)*rstd*gv[3]+bv[3]);
    *(u16x4*)(y + base) = ov;
    return;
  }
  transpose_tile(t0, bidx, tid, tile);
}

// ---------------- fused split-K reduce(+bias+residual) -> x2 (f32) AND LayerNorm -> h2 (bf16) ----------------
__global__ __launch_bounds__(256) void ln2_fused(const u16* __restrict__ P0, const u16* __restrict__ P1,
                                                 const u16* __restrict__ P2, const u16* __restrict__ P3,
                                                 const float* __restrict__ bias, const float* __restrict__ xres,
                                                 const float* __restrict__ g, const float* __restrict__ b,
                                                 float* __restrict__ x2, u16* __restrict__ h2){
  int row = blockIdx.x, tid = threadIdx.x;
  size_t base = (size_t)row*1024 + tid*4;
  u16x4 a0 = *(const u16x4*)(P0 + base);
  u16x4 a1 = *(const u16x4*)(P1 + base);
  u16x4 a2 = *(const u16x4*)(P2 + base);
  u16x4 a3 = *(const u16x4*)(P3 + base);
  f32x4 rv = *(const f32x4*)(xres + base);
  f32x4 bv = *(const f32x4*)(bias + tid*4);
  f32x4 v;
  #pragma unroll
  for (int j=0;j<4;j++) v[j] = (bf2f(a0[j])+bf2f(a1[j])) + (bf2f(a2[j])+bf2f(a3[j])) + bv[j] + rv[j];
  *(f32x4*)(x2 + base) = v;
  float s  = v[0]+v[1]+v[2]+v[3];
  float s2 = v[0]*v[0]+v[1]*v[1]+v[2]*v[2]+v[3]*v[3];
  #pragma unroll
  for (int off=32; off>0; off>>=1){ s += __shfl_xor(s, off); s2 += __shfl_xor(s2, off); }
  __shared__ float ls[4], ls2[4];
  if ((tid & 63) == 0){ ls[tid>>6] = s; ls2[tid>>6] = s2; }
  __syncthreads();
  float ts = ls[0]+ls[1]+ls[2]+ls[3];
  float ts2 = ls2[0]+ls2[1]+ls2[2]+ls2[3];
  float mean = ts*(1.f/1024.f);
  float var  = ts2*(1.f/1024.f) - mean*mean;
  float rstd = rsqrtf(var + 1e-5f);
  f32x4 gv = *(const f32x4*)(g + tid*4);
  f32x4 bb = *(const f32x4*)(b + tid*4);
  u16x4 ov;
  #pragma unroll
  for (int j=0;j<4;j++) ov[j] = f2bf((v[j]-mean)*rstd*gv[j]+bb[j]);
  *(u16x4*)(h2 + base) = ov;
}

// ---------------- GEMM: C[M][N] = A[M][K] * BT[N][K]^T (+ bias) ----------------
// 128x128 tile, BK=64, 8 waves, 2-buffer LDS, T2 both-sides XOR swizzle, T1 XCD block swizzle.
// T4 counted-vmcnt 2-deep pipeline: tile t+1's loads stay in flight across barriers
// (s_waitcnt vmcnt(4) retires exactly tile t's 4 loads/thread); STAGE refills the
// just-computed buffer behind a raw s_barrier. No vmcnt(0) drain in the main loop.
// EPI 0: +bias -> bf16.  1: gelu(+bias) -> bf16.  3: split-K bf16 PARTIAL (no bias), z at out+z*pstride.
template<int EPI>
__global__ __launch_bounds__(512, 4) void gemm_bt(const u16* __restrict__ A, const u16* __restrict__ BT,
                                                  const float* __restrict__ bias, const float* __restrict__ res,
                                                  void* __restrict__ out, int N, int K, size_t pstride){
  __shared__ u16 As[2][128*64];
  __shared__ u16 Bs[2][128*64];
  int tid = threadIdx.x;
  int w = tid >> 6, lane = tid & 63;

  unsigned flat = blockIdx.x + gridDim.x*(blockIdx.y + gridDim.y*blockIdx.z);
  unsigned nwg  = gridDim.x*gridDim.y*gridDim.z;
  unsigned logical = (flat & 7)*(nwg >> 3) + (flat >> 3);
  unsigned bx = logical % gridDim.x;
  unsigned rem = logical / gridDim.x;
  unsigned by = rem % gridDim.y;
  unsigned bz = rem / gridDim.y;

  int m0 = bx * 128, n0 = by * 128;
  int Kc = K / gridDim.z;
  int kbase = bz * Kc;
  int nt = Kc / 64;

  f32x4 acc[2][4] = {};

  int l3 = lane >> 3, l7 = lane & 7;
  const u16* aSrc = A  + (size_t)(m0 + w*16 + l3)*K + kbase + (l7 ^ l3)*8;
  const u16* bSrc = BT + (size_t)(n0 + w*16 + l3)*K + kbase + (l7 ^ l3)*8;
  int r0 = (w>>1)*32, c0 = (w&1)*64;
  int lrow = lane & 15, g4 = lane >> 4;
  int swz = (lrow & 7) << 4;

  auto STAGE = [&](int kt, int buf){
    int k0 = kt*64;
    u16* aD = As[buf] + w*16*64;
    u16* bD = Bs[buf] + w*16*64;
    gload_lds16(aSrc + k0,               aD);
    gload_lds16(aSrc + (size_t)8*K + k0, aD + 8*64);
    gload_lds16(bSrc + k0,               bD);
    gload_lds16(bSrc + (size_t)8*K + k0, bD + 8*64);
  };
  auto COMPUTE = [&](int buf){
    const char* Ab = (const char*)As[buf];
    const char* Bb = (const char*)Bs[buf];
    #pragma unroll
    for (int kk=0; kk<2; kk++){
      int ko = (kk*64 + g4*16) ^ swz;
      bf16x8 af[2], bfv[4];
      #pragma unroll
      for (int mi=0;mi<2;mi++) af[mi]  = *(const bf16x8*)(Ab + (r0 + mi*16 + lrow)*128 + ko);
      #pragma unroll
      for (int ni=0;ni<4;ni++)  bfv[ni] = *(const bf16x8*)(Bb + (c0 + ni*16 + lrow)*128 + ko);
      #pragma unroll
      for (int mi=0;mi<2;mi++)
        #pragma unroll
        for (int ni=0;ni<4;ni++)
          acc[mi][ni] = __builtin_amdgcn_mfma_f32_16x16x32_bf16(af[mi], bfv[ni], acc[mi][ni], 0, 0, 0);
    }
  };

  // 2-deep prologue: 8 loads/thread in flight
  STAGE(0, 0);
  STAGE(1, 1);
  for (int t = 0; t < nt; ++t){
    int buf = t & 1;
    if (t + 1 < nt) { asm volatile("s_waitcnt vmcnt(4)" ::: "memory"); }  // tile t landed; t+1 in flight
    else            { asm volatile("s_waitcnt vmcnt(0)" ::: "memory"); }
    __builtin_amdgcn_s_barrier();            // all waves' tile-t writes visible
    __builtin_amdgcn_sched_barrier(0);       // pin: no ds_read hoisted above the wait (rule 18)
    COMPUTE(buf);
    __builtin_amdgcn_s_barrier();            // all waves done reading buf (no vmcnt drain)
    if (t + 2 < nt) STAGE(t+2, buf);
  }

  int lgr = lane >> 4;
  u16* pout = (EPI == 3) ? ((u16*)out + (size_t)bz * pstride) : (u16*)out;
  #pragma unroll
  for (int mi=0;mi<2;mi++){
    #pragma unroll
    for (int j=0;j<4;j++){
      int row = m0 + r0 + mi*16 + lgr*4 + j;
      #pragma unroll
      for (int ni=0;ni<4;ni++){
        int col = n0 + c0 + ni*16 + lrow;
        size_t idx = (size_t)row*N + col;
        if constexpr (EPI == 3){
          pout[idx] = f2bf(acc[mi][ni][j]);
        } else {
          float v = acc[mi][ni][j] + bias[col];
          if constexpr (EPI == 0){
            ((u16*)out)[idx] = f2bf(v);
          } else {
            v = 0.5f * v * (1.f + erff(v * 0.70710678118654752f));
            ((u16*)out)[idx] = f2bf(v);
          }
        }
      }
    }
  }
}

// ---------------- split-K reduction: out = sum(4 partials) + bias + res (f32 out) ----------------
__global__ __launch_bounds__(256) void reduce4(const u16* __restrict__ P0, const u16* __restrict__ P1,
                                               const u16* __restrict__ P2, const u16* __restrict__ P3,
                                               const float* __restrict__ bias, const float* __restrict__ res,
                                               float* __restrict__ out){
  size_t i = ((size_t)blockIdx.x*256 + threadIdx.x)*4;
  u16x4 a = *(const u16x4*)(P0 + i);
  u16x4 b = *(const u16x4*)(P1 + i);
  u16x4 c = *(const u16x4*)(P2 + i);
  u16x4 d = *(const u16x4*)(P3 + i);
  f32x4 rv = *(const f32x4*)(res + i);
  f32x4 bv = *(const f32x4*)(bias + (i & 1023));
  f32x4 o;
  #pragma unroll
  for (int j=0;j<4;j++) o[j] = (bf2f(a[j]) + bf2f(b[j])) + (bf2f(c[j]) + bf2f(d[j])) + bv[j] + rv[j];
  *(f32x4*)(out + i) = o;
}

// ---------------- attention: S^T chunk sums + Ks sums, WITH 3 weight transposes riding the grid ----------------
__global__ __launch_bounds__(256) void attn_chunksum(TD d1, TD d2, TD d3,
                                                     const u16* __restrict__ qkv,
                                                     float* __restrict__ S, float* __restrict__ Ks){
  __shared__ u16 KT[64*72];  // [d][t] bf16, elup'd  (transpose path reuses as 64x65 tile)
  __shared__ u16 VT[64*72];  // [e][t] bf16 (raw)
  int bidx = blockIdx.x, tid = threadIdx.x;
  if (bidx >= 512){
    int bb = bidx - 512;
    TD d;
    if (bb < d1.ntiles) d = d1;
    else { bb -= d1.ntiles;
      if (bb < d2.ntiles) d = d2;
      else { bb -= d2.ntiles; d = d3; } }
    transpose_tile(d, bb, tid, (u16(*)[65])KT);
    return;
  }
  int c = bidx & 31, h = bidx >> 5;
  int t = tid >> 2, seg = tid & 3, e0 = seg*16;
  size_t rowb = (size_t)(c*64 + t)*3072 + h*64 + e0;
  u16x8 k0 = *(const u16x8*)(qkv + rowb + 1024);
  u16x8 k1 = *(const u16x8*)(qkv + rowb + 1032);
  u16x8 v0 = *(const u16x8*)(qkv + rowb + 2048);
  u16x8 v1 = *(const u16x8*)(qkv + rowb + 2056);
  #pragma unroll
  for (int i=0;i<8;i++){
    KT[(e0 + i)*72 + t]     = f2bf(elup(bf2f(k0[i])));
    KT[(e0 + 8 + i)*72 + t] = f2bf(elup(bf2f(k1[i])));
    VT[(e0 + i)*72 + t]     = v0[i];
    VT[(e0 + 8 + i)*72 + t] = v1[i];
  }
  __syncthreads();

  int w = tid >> 6, lane = tid & 63;
  int lr = lane & 15, lk = (lane>>4)*8, g = lane >> 4, cl = lane & 15;
  bf16x8 av_[2];
  #pragma unroll
  for (int kk=0;kk<2;kk++) av_[kk] = *(const bf16x8*)(VT + (w*16 + lr)*72 + kk*32 + lk);
  f32x4 acc[4] = {};
  #pragma unroll
  for (int di=0;di<4;di++){
    #pragma unroll
    for (int kk=0;kk<2;kk++){
      bf16x8 bk = *(const bf16x8*)(KT + (di*16 + lr)*72 + kk*32 + lk);
      acc[di] = __builtin_amdgcn_mfma_f32_16x16x32_bf16(av_[kk], bk, acc[di], 0, 0, 0);
    }
  }
  size_t base = (size_t)(h*32 + c)*4096;
  #pragma unroll
  for (int di=0;di<4;di++)
    #pragma unroll
    for (int j=0;j<4;j++)
      S[base + (size_t)(w*16 + g*4 + j)*64 + di*16 + cl] = acc[di][j];

  float s = 0.f;
  #pragma unroll
  for (int i=0;i<16;i++) s += bf2f(KT[t*72 + e0 + i]);
  s += __shfl_xor(s, 1); s += __shfl_xor(s, 2);
  if (seg == 0) Ks[(size_t)(h*32 + c)*64 + t] = s;
}

// ---------------- attention: exclusive prefix over chunks (per head, element-parallel) ----------------
__global__ __launch_bounds__(256) void attn_prefix(float* __restrict__ S, float* __restrict__ Ks){
  int g = blockIdx.x, h = blockIdx.y, tid = threadIdx.x;
  size_t hb = (size_t)h * 32 * 4096;
  int idx = g*256 + tid;
  float run = 0.f;
  for (int c=0; c<32; c++){
    size_t p = hb + (size_t)c*4096 + idx;
    float v = S[p]; S[p] = run; run += v;
  }
  if (g == 0 && tid < 64){
    float r2 = 0.f;
    for (int c=0; c<32; c++){
      size_t p = (size_t)(h*32 + c)*64 + tid;
      float v = Ks[p]; Ks[p] = r2; r2 += v;
    }
  }
}

// ---------------- attention: O = Q*S_prev^T + tril(QK^T)V, den = Q*kp + rowsum(A); MFMA ----------------
__global__ __launch_bounds__(256) void attn_out(const u16* __restrict__ qkv, const float* __restrict__ S,
                                                const float* __restrict__ Ks, u16* __restrict__ o){
  __shared__ u16 Qs [64*72];
  __shared__ u16 Ksh[64*72];
  __shared__ u16 VT [64*72];
  __shared__ u16 SpT[64*72];
  __shared__ u16 Am [64*72];
  __shared__ float kp[64], den[64];
  int c = blockIdx.x, h = blockIdx.y, tid = threadIdx.x;
  int t = tid >> 2, seg = tid & 3, e0 = seg*16;

  size_t rowb = (size_t)(c*64 + t)*3072 + h*64 + e0;
  u16x8 q0 = *(const u16x8*)(qkv + rowb);
  u16x8 q1 = *(const u16x8*)(qkv + rowb + 8);
  u16x8 k0 = *(const u16x8*)(qkv + rowb + 1024);
  u16x8 k1 = *(const u16x8*)(qkv + rowb + 1032);
  u16x8 v0 = *(const u16x8*)(qkv + rowb + 2048);
  u16x8 v1 = *(const u16x8*)(qkv + rowb + 2056);
  #pragma unroll
  for (int i=0;i<8;i++){
    Qs [t*72 + e0 + i]     = f2bf(elup(bf2f(q0[i])));
    Qs [t*72 + e0 + 8 + i] = f2bf(elup(bf2f(q1[i])));
    Ksh[t*72 + e0 + i]     = f2bf(elup(bf2f(k0[i])));
    Ksh[t*72 + e0 + 8 + i] = f2bf(elup(bf2f(k1[i])));
    VT [(e0 + i)*72 + t]     = v0[i];
    VT [(e0 + 8 + i)*72 + t] = v1[i];
  }
  size_t sbase = (size_t)(h*32 + c)*4096;
  {
    const f32x4* sp = (const f32x4*)(S + sbase + (size_t)t*64 + e0);
    #pragma unroll
    for (int qd=0;qd<4;qd++){
      f32x4 v = sp[qd];
      #pragma unroll
      for (int j=0;j<4;j++) SpT[t*72 + e0 + qd*4 + j] = f2bf(v[j]);
    }
  }
  if (tid < 64) kp[tid] = Ks[(size_t)(h*32 + c)*64 + tid];
  __syncthreads();

  int w = tid >> 6, lane = tid & 63;
  int lr = lane & 15, lk = (lane>>4)*8, g = lane >> 4, cl = lane & 15;

  bf16x8 aq[2];
  #pragma unroll
  for (int kk=0;kk<2;kk++) aq[kk] = *(const bf16x8*)(Qs + (w*16 + lr)*72 + kk*32 + lk);

  f32x4 acc[4] = {};
  #pragma unroll
  for (int ni=0;ni<4;ni++){
    #pragma unroll
    for (int kk=0;kk<2;kk++){
      bf16x8 bs = *(const bf16x8*)(SpT + (ni*16 + lr)*72 + kk*32 + lk);
      acc[ni] = __builtin_amdgcn_mfma_f32_16x16x32_bf16(aq[kk], bs, acc[ni], 0, 0, 0);
    }
  }
  #pragma unroll
  for (int si=0;si<4;si++){
    f32x4 qk = {};
    #pragma unroll
    for (int kk=0;kk<2;kk++){
      bf16x8 bk = *(const bf16x8*)(Ksh + (si*16 + lr)*72 + kk*32 + lk);
      qk = __builtin_amdgcn_mfma_f32_16x16x32_bf16(aq[kk], bk, qk, 0, 0, 0);
    }
    #pragma unroll
    for (int j=0;j<4;j++){
      int rowt = w*16 + g*4 + j;
      int scol = si*16 + cl;
      Am[rowt*72 + scol] = f2bf((scol <= rowt) ? qk[j] : 0.f);
    }
  }
  __syncthreads();

  {
    float dsum = 0.f;
    #pragma unroll
    for (int i=0;i<16;i++) dsum += bf2f(Am[t*72 + e0 + i]);
    #pragma unroll
    for (int i=0;i<16;i++) dsum += bf2f(Qs[t*72 + e0 + i]) * kp[e0 + i];
    dsum += __shfl_xor(dsum, 1); dsum += __shfl_xor(dsum, 2);
    if (seg == 0) den[t] = dsum;
  }
  {
    bf16x8 aa[2];
    #pragma unroll
    for (int kk=0;kk<2;kk++) aa[kk] = *(const bf16x8*)(Am + (w*16 + lr)*72 + kk*32 + lk);
    #pragma unroll
    for (int ni=0;ni<4;ni++){
      #pragma unroll
      for (int kk=0;kk<2;kk++){
        bf16x8 bv = *(const bf16x8*)(VT + (ni*16 + lr)*72 + kk*32 + lk);
        acc[ni] = __builtin_amdgcn_mfma_f32_16x16x32_bf16(aa[kk], bv, acc[ni], 0, 0, 0);
      }
    }
  }
  __syncthreads();

  #pragma unroll
  for (int j=0;j<4;j++){
    int rowt = w*16 + g*4 + j;
    float inv = 1.f/(den[rowt] + 1e-6f);
    #pragma unroll
    for (int ni=0;ni<4;ni++)
      o[(size_t)(c*64 + rowt)*1024 + h*64 + ni*16 + cl] = f2bf(acc[ni][j]*inv);
  }
}

// ---------------- launch ----------------
extern "C" void kernel_launch(void* const* d_in, const int* in_sizes, int n_in,
                              void* d_out, int out_size, void* d_ws, size_t ws_size,
                              hipStream_t stream) {
  (void)in_sizes; (void)n_in; (void)out_size; (void)ws_size;
  const float* x     = (const float*)d_in[0];
  const float* qkv_w = (const float*)d_in[1];
  const float* qkv_b = (const float*)d_in[2];
  const float* out_w = (const float*)d_in[3];
  const float* out_b = (const float*)d_in[4];
  const float* ln1_g = (const float*)d_in[5];
  const float* ln1_b = (const float*)d_in[6];
  const float* ln2_g = (const float*)d_in[7];
  const float* ln2_b = (const float*)d_in[8];
  const float* w1    = (const float*)d_in[9];
  const float* b1    = (const float*)d_in[10];
  const float* w2    = (const float*)d_in[11];
  const float* b2    = (const float*)d_in[12];

  char* ws = (char*)d_ws;
  u16*   wT_qkv = (u16*)  (ws);              // [0, 6291456)        dead after qkv GEMM
  u16*   wT_out = (u16*)  (ws +  6291456);   // [6291456, 8388608)  dead after out-proj
  u16*   wT_w1  = (u16*)  (ws +  8388608);   // [8388608, 16777216) dead after MLP1
  u16*   wT_w2  = (u16*)  (ws + 16777216);   // [16777216, 25165824)
  u16*   h1     = (u16*)  (ws + 25165824);   // [25165824, 29360128) bf16; reused as o
  u16*   qkv    = (u16*)  (ws + 29360128);   // [29360128, 41943040) bf16; dead after attn_out
  float* Ssum   = (float*)(ws + 41943040);   // [41943040, 50331648) f32 S^T chunks; dead after attn_out
  float* ksum   = (float*)(ws + 50331648);   // [50331648, 50462720)
  float* x2     = (float*)(ws + 50462720);   // [50462720, 58851328) f32
  u16*   h2     = (u16*)  (ws + 58851328);   // [58851328, 63045632) bf16
  u16*   o      = h1;
  u16*   a1     = qkv;                        // 2048x4096 bf16 over dead qkv+Ssum
  u16*   Pa0    = (u16*)(ws + 29360128);      // out-proj split-4 partials (dead qkv+Ssum, pre-a1)
  size_t PaStride = 2097152;                  // elements
  u16*   Pm0    = (u16*)(ws);                 // MLP2 split-4 partials over dead wT regions
  u16*   Pm1    = (u16*)(ws +  4194304);
  u16*   Pm2    = (u16*)(ws +  8388608);
  u16*   Pm3    = (u16*)(ws + 12582912);
  size_t PmStride = 2097152;                  // elements
  float* outp   = (float*)d_out;

  TD t0{qkv_w, wT_qkv, 1024, 3072,  48,  768};
  TD t1{out_w, wT_out, 1024, 1024,  16,  256};
  TD t2{w1,    wT_w1,  1024, 4096,  64, 1024};
  TD t3{w2,    wT_w2,  4096, 1024,  16, 1024};

  // prep1: qkv_w transpose (768) + LN1 (2048)
  prep1<<<2816, 256, 0, stream>>>(t0, x, ln1_g, ln1_b, h1);

  gemm_bt<0><<<dim3(16, 24, 1), 512, 0, stream>>>(h1, wT_qkv, qkv_b, nullptr, qkv, 3072, 1024, 0);

  // chunksum (512 attn blocks) + out_w/w1/w2 transposes (2304 tiles) share one dispatch
  attn_chunksum<<<2816, 256, 0, stream>>>(t1, t2, t3, qkv, Ssum, ksum);
  attn_prefix  <<<dim3(16, 16), 256, 0, stream>>>(Ssum, ksum);
  attn_out     <<<dim3(32, 16), 256, 0, stream>>>(qkv, Ssum, ksum, o);

  gemm_bt<3><<<dim3(16, 8, 4), 512, 0, stream>>>(o, wT_out, nullptr, nullptr, Pa0, 1024, 1024, PaStride);
  ln2_fused<<<2048, 256, 0, stream>>>(Pa0, Pa0 + PaStride, Pa0 + 2*PaStride, Pa0 + 3*PaStride,
                                      out_b, x, ln2_g, ln2_b, x2, h2);

  gemm_bt<1><<<dim3(16, 32, 1), 512, 0, stream>>>(h2, wT_w1, b1, nullptr, a1, 4096, 1024, 0);

  gemm_bt<3><<<dim3(16, 8, 4), 512, 0, stream>>>(a1, wT_w2, nullptr, nullptr, Pm0, 1024, 4096, PmStride);
  reduce4<<<2048, 256, 0, stream>>>(Pm0, Pm1, Pm2, Pm3, b2, x2, outp);
}